// Round 12
// baseline (462.912 us; speedup 1.0000x reference)
//
#include <hip/hip_runtime.h>

#define B_ 32
#define Q_ 128
#define S_ 2048
#define C_ 1024
#define D_ 1024

typedef __attribute__((ext_vector_type(8))) short bf16x8;
typedef __attribute__((ext_vector_type(4))) float f32x4;

static __device__ __forceinline__ unsigned short f2bf(float f) {
  unsigned int u = __float_as_uint(f);
  u = (u + 0x7FFFu + ((u >> 16) & 1u)) >> 16;
  return (unsigned short)u;
}
static __device__ __forceinline__ float bf2f(unsigned short h) {
  return __uint_as_float(((unsigned int)h) << 16);
}

// ---------------------------------------------------------------------------
// BK = 32 GEMM tiles: LDS [128][32] bf16, 64B rows.
// Swizzle: chunk (16B) index c in row r stored at chunk (c ^ ((r>>1)&3)).
// Fragment reads (16 lanes, consecutive rows, fixed chunk) then hit each bank
// exactly 2-way (free). 32KB LDS for split GEMMs -> 4-5 blocks/CU.
// ---------------------------------------------------------------------------

// Stage 16 consecutive f32 (row r, f32 cols sc..sc+15, sc in {0,16}) into
// hi+lo bf16 tiles.
static __device__ __forceinline__ void stage16s(unsigned short* hi, unsigned short* lo,
                                                const float* s, int r, int sc) {
  float v[16];
#pragma unroll
  for (int j = 0; j < 4; ++j) {
    f32x4 t = *(const f32x4*)(s + j * 4);
    v[j * 4 + 0] = t[0]; v[j * 4 + 1] = t[1]; v[j * 4 + 2] = t[2]; v[j * 4 + 3] = t[3];
  }
  unsigned short h[16], l[16];
#pragma unroll
  for (int e = 0; e < 16; ++e) {
    h[e] = f2bf(v[e]);
    float rres = v[e] - bf2f(h[e]);
    l[e] = f2bf(rres);
  }
  bf16x8 vh0, vh1, vl0, vl1;
#pragma unroll
  for (int e = 0; e < 8; ++e) {
    vh0[e] = (short)h[e]; vh1[e] = (short)h[e + 8];
    vl0[e] = (short)l[e]; vl1[e] = (short)l[e + 8];
  }
  const int sw = (r >> 1) & 3;
  const int ch0 = sc >> 3;  // 0 or 2
  char* hrow = (char*)hi + r * 64;
  char* lrow = (char*)lo + r * 64;
  *(bf16x8*)(hrow + (((ch0 + 0) ^ sw) << 4)) = vh0;
  *(bf16x8*)(hrow + (((ch0 + 1) ^ sw) << 4)) = vh1;
  *(bf16x8*)(lrow + (((ch0 + 0) ^ sw) << 4)) = vl0;
  *(bf16x8*)(lrow + (((ch0 + 1) ^ sw) << 4)) = vl1;
}

// Stage a 128x32 bf16 tile by 32B copies (rows K-contiguous).
static __device__ __forceinline__ void stage_copy32(unsigned short* dst,
                                                    const unsigned short* base,
                                                    long rstride, int kt, int tid) {
  const int r = tid >> 1;
  const int h = tid & 1;  // bf16 cols h*16..h*16+15
  const unsigned short* s = base + (long)r * rstride + kt + h * 16;
  bf16x8 a = *(const bf16x8*)s;
  bf16x8 b = *(const bf16x8*)(s + 8);
  const int sw = (r >> 1) & 3;
  char* row = (char*)dst + r * 64;
  *(bf16x8*)(row + (((h * 2 + 0) ^ sw) << 4)) = a;
  *(bf16x8*)(row + (((h * 2 + 1) ^ sw) << 4)) = b;
}

// C[m,n] = sum_k A[m,k]*B[n,k].
// AM/BM: 0 = f32 split (hi+lo, 3-pass MFMA), 2 = bf16 copy (1-pass).
// FUSE: write staged B hi-tile transposed to fuseOut[bz][k][n] (free ctxT).
template <int AM, int BM, bool FUSE>
__global__ __launch_bounds__(256, 4)
void gemm_k(const void* __restrict__ Aip, const void* __restrict__ Bip,
            float* __restrict__ outp, int K,
            long aBatch, long bBatch, long outBatch,
            long aRstride, long bRstride, long outRstride, int remapQB,
            unsigned short* __restrict__ fuseOut, long fuseRstride) {
  extern __shared__ char smem[];
  unsigned short* sA_hi = (unsigned short*)smem;  // [128][32]
  unsigned short* ptr = sA_hi + 128 * 32;
  unsigned short* sA_lo = nullptr;
  if constexpr (AM == 0) { sA_lo = ptr; ptr += 128 * 32; }
  unsigned short* sB_hi = ptr; ptr += 128 * 32;
  unsigned short* sB_lo = nullptr;
  if constexpr (BM == 0) { sB_lo = ptr; }

  const int tid = threadIdx.x;
  const int lane = tid & 63;
  const int wid = tid >> 6;
  const int wr = wid >> 1;
  const int wc = wid & 1;
  const int m0 = blockIdx.y * 128;
  const int n0 = blockIdx.x * 128;
  const int bz = blockIdx.z;
  const int frow = lane & 15;
  const int cc = lane >> 4;  // K-chunk 0..3

  f32x4 acc[4][4];
#pragma unroll
  for (int i = 0; i < 4; ++i)
#pragma unroll
    for (int j = 0; j < 4; ++j) acc[i][j] = (f32x4){0.f, 0.f, 0.f, 0.f};

  for (int kt = 0; kt < K; kt += 32) {
    // ---- stage A ----
    if constexpr (AM == 0) {
      const float* Af = (const float*)Aip + (long)bz * aBatch;
      const int r = tid >> 1;
      const int sc = (tid & 1) << 4;  // 0 or 16 (f32)
      stage16s(sA_hi, sA_lo, Af + (long)(m0 + r) * aRstride + kt + sc, r, sc);
    } else {
      const unsigned short* Ab = (const unsigned short*)Aip + (long)bz * aBatch;
      stage_copy32(sA_hi, Ab + (long)m0 * aRstride, aRstride, kt, tid);
    }
    // ---- stage B ----
    if constexpr (BM == 0) {
      const float* Bf = (const float*)Bip + (long)bz * bBatch;
      const int r = tid >> 1;
      const int sc = (tid & 1) << 4;
      stage16s(sB_hi, sB_lo, Bf + (long)(n0 + r) * bRstride + kt + sc, r, sc);
    } else {
      const unsigned short* Bb = (const unsigned short*)Bip + (long)bz * bBatch;
      stage_copy32(sB_hi, Bb + (long)n0 * bRstride, bRstride, kt, tid);
    }
    __syncthreads();

    bf16x8 ah[4], bh[4], al[4], bl[4];
#pragma unroll
    for (int i = 0; i < 4; ++i) {
      const int row = wr * 64 + i * 16 + frow;
      const int off = row * 64 + ((cc ^ ((row >> 1) & 3)) << 4);
      ah[i] = *(const bf16x8*)((const char*)sA_hi + off);
      if constexpr (AM == 0) al[i] = *(const bf16x8*)((const char*)sA_lo + off);
    }
#pragma unroll
    for (int j = 0; j < 4; ++j) {
      const int row = wc * 64 + j * 16 + frow;
      const int off = row * 64 + ((cc ^ ((row >> 1) & 3)) << 4);
      bh[j] = *(const bf16x8*)((const char*)sB_hi + off);
      if constexpr (BM == 0) bl[j] = *(const bf16x8*)((const char*)sB_lo + off);
    }
#pragma unroll
    for (int i = 0; i < 4; ++i)
#pragma unroll
      for (int j = 0; j < 4; ++j) {
        acc[i][j] = __builtin_amdgcn_mfma_f32_16x16x32_bf16(ah[i], bh[j], acc[i][j], 0, 0, 0);
        if constexpr (BM == 0)
          acc[i][j] = __builtin_amdgcn_mfma_f32_16x16x32_bf16(ah[i], bl[j], acc[i][j], 0, 0, 0);
        if constexpr (AM == 0)
          acc[i][j] = __builtin_amdgcn_mfma_f32_16x16x32_bf16(al[i], bh[j], acc[i][j], 0, 0, 0);
      }

    // ---- fused transposed write-out of staged B hi-tile ----
    // fuseOut[bz][kt+kl][n0 + nf .. nf+15], kl = tid>>3 (0..31), nf = (tid&7)*16.
    // LDS element (row, bf16 col k): byte = row*64 + ((((2k)>>4)^((row>>1)&3))<<4) + ((2k)&15)
    if constexpr (FUSE) {
      const int kl = tid >> 3;
      const int nf = (tid & 7) * 16;
      const int cb = kl * 2;  // byte col
      unsigned short vals[16];
#pragma unroll
      for (int i = 0; i < 16; ++i) {
        const int row = nf + i;
        vals[i] = *(const unsigned short*)((const char*)sB_hi + row * 64 +
                   ((((cb >> 4) ^ ((row >> 1) & 3)) << 4) + (cb & 15)));
      }
      unsigned short* dst = fuseOut + ((long)bz * K + kt + kl) * fuseRstride + n0 + nf;
      *(bf16x8*)(dst + 0) = *(const bf16x8*)(vals + 0);
      *(bf16x8*)(dst + 8) = *(const bf16x8*)(vals + 8);
    }
    __syncthreads();
  }

  float* out = outp + (long)bz * outBatch;
#pragma unroll
  for (int i = 0; i < 4; ++i) {
#pragma unroll
    for (int rr = 0; rr < 4; ++rr) {
      const int grow = m0 + wr * 64 + i * 16 + ((lane >> 4) << 2) + rr;
      const long orow = remapQB ? ((long)(grow & 31) * 128 + (grow >> 5)) : (long)grow;
      float* orp = out + orow * outRstride;
#pragma unroll
      for (int j = 0; j < 4; ++j) {
        const int col = n0 + wc * 64 + j * 16 + (lane & 15);
        orp[col] = acc[i][j][rr];
      }
    }
  }
}

// ---------------------------------------------------------------------------
// Scan (round-9 proven, verbatim): 512 threads/block, 4 cols/thread.
// asm global_load_dwordx4 prefetch depth 2 + counted vmcnt; 3 VMEM ops/row
// (1 load + 2 stores) -> ladder 1/3/5; one raw s_barrier per row; parity
// double-buffered LDS (m,s); exact wave max; plain fmax/add butterflies.
// ---------------------------------------------------------------------------
template <int VM>
static __device__ __forceinline__ void scan_row(
    float* __restrict__ attn, unsigned short* __restrict__ attnb,
    int b, int q, int lane, int wid, int s0,
    const bool* msk, float* acc, f32x4& buf, float2 (&red)[2][8]) {
  const float L2E = 1.4426950408889634f;

  if constexpr (VM == 1)      asm volatile("s_waitcnt vmcnt(1)" ::: "memory");
  else if constexpr (VM == 3) asm volatile("s_waitcnt vmcnt(3)" ::: "memory");
  else                        asm volatile("s_waitcnt vmcnt(5)" ::: "memory");
  __builtin_amdgcn_sched_barrier(0);

  float adj[4];
#pragma unroll
  for (int j = 0; j < 4; ++j)
    adj[j] = msk[j] ? -1e30f : (buf[j] - acc[j]);

  int pr = q + 2; if (pr > Q_ - 1) pr = Q_ - 1;
  const float* pp = attn + ((long)(pr * B_ + b)) * S_ + s0;
  asm volatile("global_load_dwordx4 %0, %1, off"
               : "=&v"(buf)
               : "v"(pp), "v"(adj[0]), "v"(adj[1]), "v"(adj[2]), "v"(adj[3])
               : "memory");

  float lm = fmaxf(fmaxf(adj[0], adj[1]), fmaxf(adj[2], adj[3]));
#pragma unroll
  for (int off = 32; off > 0; off >>= 1) lm = fmaxf(lm, __shfl_xor(lm, off));

  float e[4];
#pragma unroll
  for (int j = 0; j < 4; ++j) {
    const float x = exp2f((adj[j] - lm) * L2E);
    e[j] = msk[j] ? 0.f : x;
  }

  float ls = (e[0] + e[1]) + (e[2] + e[3]);
#pragma unroll
  for (int off = 32; off > 0; off >>= 1) ls += __shfl_xor(ls, off);

  const int p = q & 1;
  if (lane == 0) red[p][wid] = make_float2(lm, ls);
  asm volatile("s_waitcnt lgkmcnt(0)\n\ts_barrier" ::: "memory");

  const float2 v0 = red[p][0], v1 = red[p][1], v2 = red[p][2], v3 = red[p][3];
  const float2 v4 = red[p][4], v5 = red[p][5], v6 = red[p][6], v7 = red[p][7];
  const float M = fmaxf(fmaxf(fmaxf(v0.x, v1.x), fmaxf(v2.x, v3.x)),
                        fmaxf(fmaxf(v4.x, v5.x), fmaxf(v6.x, v7.x)));
  const float tot = v0.y * exp2f((v0.x - M) * L2E) + v1.y * exp2f((v1.x - M) * L2E) +
                    v2.y * exp2f((v2.x - M) * L2E) + v3.y * exp2f((v3.x - M) * L2E) +
                    v4.y * exp2f((v4.x - M) * L2E) + v5.y * exp2f((v5.x - M) * L2E) +
                    v6.y * exp2f((v6.x - M) * L2E) + v7.y * exp2f((v7.x - M) * L2E);
  const float scale = exp2f((lm - M) * L2E) / tot;

  f32x4 av;
#pragma unroll
  for (int j = 0; j < 4; ++j) {
    av[j] = e[j] * scale;
    acc[j] += av[j];
  }
  *(f32x4*)(attn + ((long)(q * B_ + b)) * S_ + s0) = av;
  uint2 pk;
  pk.x = (unsigned int)f2bf(av[0]) | ((unsigned int)f2bf(av[1]) << 16);
  pk.y = (unsigned int)f2bf(av[2]) | ((unsigned int)f2bf(av[3]) << 16);
  *(uint2*)(attnb + ((long)b * Q_ + q) * S_ + s0) = pk;
}

__global__ __launch_bounds__(512)
void scan_kernel(const int* __restrict__ mask, float* __restrict__ attn,
                 float* __restrict__ accum_out, unsigned short* __restrict__ attnb) {
  const int b = blockIdx.x;
  const int tid = threadIdx.x;   // 0..511
  const int lane = tid & 63;
  const int wid = tid >> 6;      // 0..7
  const int s0 = tid * 4;

  __shared__ float2 red[2][8];

  const int4 mk = *(const int4*)(mask + (long)b * S_ + s0);
  const bool msk[4] = {mk.x != 0, mk.y != 0, mk.z != 0, mk.w != 0};
  asm volatile("" :: "v"(mk.x), "v"(mk.y), "v"(mk.z), "v"(mk.w));

  float acc[4] = {0.f, 0.f, 0.f, 0.f};

  f32x4 bufE, bufO;
  const float* p0 = attn + (long)b * S_ + s0;          // row 0
  asm volatile("global_load_dwordx4 %0, %1, off" : "=&v"(bufE) : "v"(p0) : "memory");
  const float* p1 = attn + ((long)(B_ + b)) * S_ + s0; // row 1
  asm volatile("global_load_dwordx4 %0, %1, off" : "=&v"(bufO) : "v"(p1) : "memory");

  scan_row<1>(attn, attnb, b, 0, lane, wid, s0, msk, acc, bufE, red);
  scan_row<3>(attn, attnb, b, 1, lane, wid, s0, msk, acc, bufO, red);
  for (int q = 2; q < Q_; q += 2) {
    scan_row<5>(attn, attnb, b, q,     lane, wid, s0, msk, acc, bufE, red);
    scan_row<5>(attn, attnb, b, q + 1, lane, wid, s0, msk, acc, bufO, red);
  }

  f32x4 a4;
#pragma unroll
  for (int j = 0; j < 4; ++j) a4[j] = acc[j];
  *(f32x4*)(accum_out + (long)b * S_ + s0) = a4;
}

extern "C" void kernel_launch(void* const* d_in, const int* in_sizes, int n_in,
                              void* d_out, int out_size, void* d_ws, size_t ws_size,
                              hipStream_t stream) {
  const float* ctx   = (const float*)d_in[0];  // [B,S,C] f32
  const float* query = (const float*)d_in[1];  // [Q,B,D] f32
  const int*   mask  = (const int*)d_in[2];    // [B,S] int32 (bool)
  const float* W     = (const float*)d_in[3];  // [C,D] f32

  float* out = (float*)d_out;
  float* attn = out;                                      // [Q,B,S]
  float* accum_out = out + (size_t)Q_ * B_ * S_;          // [B,1,S]
  float* comp = accum_out + (size_t)B_ * S_;              // [Q,B,C]

  char* ws = (char*)d_ws;
  float* qw = (float*)ws;                                                   // [B,Q,C] f32, 16 MiB
  unsigned short* ctxT  = (unsigned short*)(ws + (size_t)16 * 1024 * 1024); // [B,C,S] bf16, 128 MiB
  unsigned short* attnb = (unsigned short*)(ws + (size_t)16 * 1024 * 1024 +
                                            (size_t)B_ * C_ * S_ * 2);      // [B,Q,S] bf16, 16 MiB

  // 1) QW[b,q,c] = sum_d query[q,b,d] * W[c,d]   (3-pass split for precision)
  gemm_k<0, 0, false><<<dim3(C_ / 128, (Q_ * B_) / 128, 1), 256, 32768, stream>>>(
      query, W, qw, D_, 0L, 0L, 0L, (long)D_, (long)D_, (long)C_, 1, nullptr, 0L);

  // 2) scores[q,b,s] = sum_c QW[b,q,c] * ctx[b,s,c]  -> attention region of
  //    d_out, AND fused ctxT[b][c][s] write-out from the staged B tiles.
  gemm_k<0, 0, true><<<dim3(S_ / 128, 1, B_), 256, 32768, stream>>>(
      qw, ctx, attn, C_, (long)Q_ * C_, (long)S_ * C_, (long)S_,
      (long)C_, (long)C_, (long)B_ * S_, 0, ctxT, (long)S_);

  // 3) sequential coverage-softmax scan (in-place attention + accum + bf16 copy)
  scan_kernel<<<B_, 512, 0, stream>>>(mask, attn, accum_out, attnb);

  // 4) composition[q,b,c] = sum_s attnb[b,q,s] * ctxT[b,c,s]
  gemm_k<2, 2, false><<<dim3(C_ / 128, 1, B_), 256, 16384, stream>>>(
      attnb, ctxT, comp, S_, (long)Q_ * S_, (long)C_ * S_, (long)C_,
      (long)S_, (long)S_, (long)B_ * C_, 0, nullptr, 0L);
}

// Round 13
// 402.951 us; speedup vs baseline: 1.1488x; 1.1488x over previous
//
#include <hip/hip_runtime.h>

#define B_ 32
#define Q_ 128
#define S_ 2048
#define C_ 1024
#define D_ 1024

typedef __attribute__((ext_vector_type(8))) short bf16x8;
typedef __attribute__((ext_vector_type(4))) float f32x4;

static __device__ __forceinline__ unsigned short f2bf(float f) {
  unsigned int u = __float_as_uint(f);
  u = (u + 0x7FFFu + ((u >> 16) & 1u)) >> 16;
  return (unsigned short)u;
}
static __device__ __forceinline__ float bf2f(unsigned short h) {
  return __uint_as_float(((unsigned int)h) << 16);
}

// async 16B global->LDS (DMA; dest = wave-uniform base + lane*16)
static __device__ __forceinline__ void gl_lds16(const float* g, float* l) {
  __builtin_amdgcn_global_load_lds(
      (const __attribute__((address_space(1))) unsigned int*)g,
      (__attribute__((address_space(3))) unsigned int*)l, 16, 0, 0);
}

// split 8 f32 (two f32x4) into hi/lo bf16x8 (rounded hi, rounded residual)
static __device__ __forceinline__ void split8(const f32x4 x0, const f32x4 x1,
                                              bf16x8& hi, bf16x8& lo) {
  float v[8] = {x0[0], x0[1], x0[2], x0[3], x1[0], x1[1], x1[2], x1[3]};
#pragma unroll
  for (int e = 0; e < 8; ++e) {
    const unsigned short h = f2bf(v[e]);
    hi[e] = (short)h;
    lo[e] = (short)f2bf(v[e] - bf2f(h));
  }
}

// ---------------------------------------------------------------------------
// f32-input split GEMM, BK=64, 128x128 tile, global_load_lds staging.
// C[m,n] = sum_k A[m,k]*B[n,k], A/B f32 rows K-contiguous.
// LDS: sA,sB = f32 [128][64] stored as LDS[r][p] = global[r][p ^ (r&7)]
// (16B chunks; source pre-swizzled so the DMA's linear lane map yields the
// swizzled layout; reads apply the same XOR -> 2-way banks, free).
// Fragments are split to bf16 hi/lo in registers; 3-pass MFMA (hh, hl, lh).
// FUSE: write bf16(B-tile) transposed to fuseOut[bz][k][n] (free ctxT).
// ---------------------------------------------------------------------------
template <bool FUSE>
__global__ __launch_bounds__(256, 2)
void gemm_f32(const float* __restrict__ Aip, const float* __restrict__ Bip,
              float* __restrict__ outp, int K,
              long aBatch, long bBatch, long outBatch,
              long aRstride, long bRstride, long outRstride, int remapQB,
              unsigned short* __restrict__ fuseOut, long fuseRstride) {
  extern __shared__ char smem[];
  float* sA = (float*)smem;            // [128][64] f32, swizzled chunks
  float* sB = sA + 128 * 64;

  const int tid = threadIdx.x;
  const int lane = tid & 63;
  const int w = tid >> 6;              // wave 0..3
  const int wr = w >> 1;
  const int wc = w & 1;
  const int m0 = blockIdx.y * 128;
  const int n0 = blockIdx.x * 128;
  const int bz = blockIdx.z;
  const int frow = lane & 15;
  const int cc = lane >> 4;            // K-subchunk 0..3

  const float* Af = Aip + (long)bz * aBatch;
  const float* Bf = Bip + (long)bz * bBatch;

  f32x4 acc[4][4];
#pragma unroll
  for (int i = 0; i < 4; ++i)
#pragma unroll
    for (int j = 0; j < 4; ++j) acc[i][j] = (f32x4){0.f, 0.f, 0.f, 0.f};

  for (int kt = 0; kt < K; kt += 64) {
    // ---- async staging: 8 issues/wave per tile, pre-swizzled source ----
#pragma unroll
    for (int i = 0; i < 8; ++i) {
      const int r = (w * 8 + i) * 4 + (lane >> 4);        // tile row 0..127
      const int csrc = (lane & 15) ^ (r & 7);             // source 16B chunk
      gl_lds16(Af + (long)(m0 + r) * aRstride + kt + csrc * 4,
               sA + (w * 8 + i) * 256);
    }
#pragma unroll
    for (int i = 0; i < 8; ++i) {
      const int r = (w * 8 + i) * 4 + (lane >> 4);
      const int csrc = (lane & 15) ^ (r & 7);
      gl_lds16(Bf + (long)(n0 + r) * bRstride + kt + csrc * 4,
               sB + (w * 8 + i) * 256);
    }
    __syncthreads();  // drains DMA (vmcnt 0) + barrier

#pragma unroll
    for (int kk = 0; kk < 2; ++kk) {
      bf16x8 ah[4], al[4], bh[4], bl[4];
#pragma unroll
      for (int i = 0; i < 4; ++i) {
        const int row = wr * 64 + i * 16 + frow;
        const int ch = kk * 8 + cc * 2;
        const f32x4 a0 = *(const f32x4*)(sA + row * 64 + ((ch ^ (row & 7)) << 2));
        const f32x4 a1 = *(const f32x4*)(sA + row * 64 + (((ch + 1) ^ (row & 7)) << 2));
        split8(a0, a1, ah[i], al[i]);
      }
#pragma unroll
      for (int j = 0; j < 4; ++j) {
        const int row = wc * 64 + j * 16 + frow;
        const int ch = kk * 8 + cc * 2;
        const f32x4 b0 = *(const f32x4*)(sB + row * 64 + ((ch ^ (row & 7)) << 2));
        const f32x4 b1 = *(const f32x4*)(sB + row * 64 + (((ch + 1) ^ (row & 7)) << 2));
        split8(b0, b1, bh[j], bl[j]);
      }
#pragma unroll
      for (int i = 0; i < 4; ++i)
#pragma unroll
        for (int j = 0; j < 4; ++j) {
          acc[i][j] = __builtin_amdgcn_mfma_f32_16x16x32_bf16(ah[i], bh[j], acc[i][j], 0, 0, 0);
          acc[i][j] = __builtin_amdgcn_mfma_f32_16x16x32_bf16(ah[i], bl[j], acc[i][j], 0, 0, 0);
          acc[i][j] = __builtin_amdgcn_mfma_f32_16x16x32_bf16(al[i], bh[j], acc[i][j], 0, 0, 0);
        }
    }

    // ---- fused bf16 transposed write-out of the B tile (ctxT) ----
    // thread: k-col = lane (0..63), n rows wid*32..+31; reads are same-row
    // across the wave -> contiguous permuted 256B -> 2-way banks (free).
    if constexpr (FUSE) {
      const int ch = lane >> 2, sub = lane & 3;
      unsigned short vals[32];
#pragma unroll
      for (int i2 = 0; i2 < 32; ++i2) {
        const int row = w * 32 + i2;
        vals[i2] = f2bf(sB[row * 64 + ((ch ^ (row & 7)) << 2) + sub]);
      }
      unsigned short* dst = fuseOut + ((long)bz * K + kt + lane) * fuseRstride +
                            n0 + w * 32;
#pragma unroll
      for (int j = 0; j < 4; ++j)
        *(bf16x8*)(dst + j * 8) = *(const bf16x8*)(vals + j * 8);
    }
    __syncthreads();
  }

  float* out = outp + (long)bz * outBatch;
#pragma unroll
  for (int i = 0; i < 4; ++i) {
#pragma unroll
    for (int rr = 0; rr < 4; ++rr) {
      const int grow = m0 + wr * 64 + i * 16 + ((lane >> 4) << 2) + rr;
      const long orow = remapQB ? ((long)(grow & 31) * 128 + (grow >> 5)) : (long)grow;
      float* orp = out + orow * outRstride;
#pragma unroll
      for (int j = 0; j < 4; ++j) {
        const int col = n0 + wc * 64 + j * 16 + (lane & 15);
        orp[col] = acc[i][j][rr];
      }
    }
  }
}

// ---------------------------------------------------------------------------
// bf16 copy GEMM (round-11 proven, verbatim): BK=64, reg staging, XOR-16B
// swizzle. Used for the composition GEMM only.
// ---------------------------------------------------------------------------
static __device__ __forceinline__ void stage_copy(unsigned short* dst,
                                                  const unsigned short* base,
                                                  long rstride, int kt, int tid) {
  const int r = tid >> 1;
  const int sc = (tid & 1) << 5;
  const int swz = (r & 7) << 4;
  const unsigned short* s = base + (long)r * rstride + kt + sc;
  char* row = (char*)dst + r * 128;
#pragma unroll
  for (int j = 0; j < 4; ++j)
    *(bf16x8*)(row + ((sc * 2 + j * 16) ^ swz)) = *(const bf16x8*)(s + j * 8);
}

__global__ __launch_bounds__(256, 2)
void gemm_bf16(const unsigned short* __restrict__ Aip, const unsigned short* __restrict__ Bip,
               float* __restrict__ outp, int K,
               long aBatch, long bBatch, long outBatch,
               long aRstride, long bRstride, long outRstride) {
  extern __shared__ char smem[];
  unsigned short* sA = (unsigned short*)smem;   // [128][64]
  unsigned short* sB = sA + 128 * 64;

  const int tid = threadIdx.x;
  const int lane = tid & 63;
  const int wid = tid >> 6;
  const int wr = wid >> 1;
  const int wc = wid & 1;
  const int m0 = blockIdx.y * 128;
  const int n0 = blockIdx.x * 128;
  const int bz = blockIdx.z;
  const int frow = lane & 15;

  f32x4 acc[4][4];
#pragma unroll
  for (int i = 0; i < 4; ++i)
#pragma unroll
    for (int j = 0; j < 4; ++j) acc[i][j] = (f32x4){0.f, 0.f, 0.f, 0.f};

  for (int kt = 0; kt < K; kt += 64) {
    stage_copy(sA, Aip + (long)bz * aBatch + (long)m0 * aRstride, aRstride, kt, tid);
    stage_copy(sB, Bip + (long)bz * bBatch + (long)n0 * bRstride, bRstride, kt, tid);
    __syncthreads();

#pragma unroll
    for (int kk = 0; kk < 2; ++kk) {
      const int kb = kk * 64 + ((lane >> 4) << 4);
      bf16x8 ah[4], bh[4];
#pragma unroll
      for (int i = 0; i < 4; ++i) {
        const int row = wr * 64 + i * 16 + frow;
        ah[i] = *(const bf16x8*)((const char*)sA + row * 128 + (kb ^ ((row & 7) << 4)));
      }
#pragma unroll
      for (int j = 0; j < 4; ++j) {
        const int row = wc * 64 + j * 16 + frow;
        bh[j] = *(const bf16x8*)((const char*)sB + row * 128 + (kb ^ ((row & 7) << 4)));
      }
#pragma unroll
      for (int i = 0; i < 4; ++i)
#pragma unroll
        for (int j = 0; j < 4; ++j)
          acc[i][j] = __builtin_amdgcn_mfma_f32_16x16x32_bf16(ah[i], bh[j], acc[i][j], 0, 0, 0);
    }
    __syncthreads();
  }

  float* out = outp + (long)bz * outBatch;
#pragma unroll
  for (int i = 0; i < 4; ++i) {
#pragma unroll
    for (int rr = 0; rr < 4; ++rr) {
      const int grow = m0 + wr * 64 + i * 16 + ((lane >> 4) << 2) + rr;
      float* orp = out + (long)grow * outRstride;
#pragma unroll
      for (int j = 0; j < 4; ++j) {
        const int col = n0 + wc * 64 + j * 16 + (lane & 15);
        orp[col] = acc[i][j][rr];
      }
    }
  }
}

// ---------------------------------------------------------------------------
// Scan (round-9/11 proven, verbatim): 512 threads/block, 4 cols/thread.
// asm prefetch depth 2 + counted vmcnt (3 VMEM/row -> ladder 1/3/5); one raw
// s_barrier per row; parity double-buffered LDS (m,s); exact wave max.
// ---------------------------------------------------------------------------
template <int VM>
static __device__ __forceinline__ void scan_row(
    float* __restrict__ attn, unsigned short* __restrict__ attnb,
    int b, int q, int lane, int wid, int s0,
    const bool* msk, float* acc, f32x4& buf, float2 (&red)[2][8]) {
  const float L2E = 1.4426950408889634f;

  if constexpr (VM == 1)      asm volatile("s_waitcnt vmcnt(1)" ::: "memory");
  else if constexpr (VM == 3) asm volatile("s_waitcnt vmcnt(3)" ::: "memory");
  else                        asm volatile("s_waitcnt vmcnt(5)" ::: "memory");
  __builtin_amdgcn_sched_barrier(0);

  float adj[4];
#pragma unroll
  for (int j = 0; j < 4; ++j)
    adj[j] = msk[j] ? -1e30f : (buf[j] - acc[j]);

  int pr = q + 2; if (pr > Q_ - 1) pr = Q_ - 1;
  const float* pp = attn + ((long)(pr * B_ + b)) * S_ + s0;
  asm volatile("global_load_dwordx4 %0, %1, off"
               : "=&v"(buf)
               : "v"(pp), "v"(adj[0]), "v"(adj[1]), "v"(adj[2]), "v"(adj[3])
               : "memory");

  float lm = fmaxf(fmaxf(adj[0], adj[1]), fmaxf(adj[2], adj[3]));
#pragma unroll
  for (int off = 32; off > 0; off >>= 1) lm = fmaxf(lm, __shfl_xor(lm, off));

  float e[4];
#pragma unroll
  for (int j = 0; j < 4; ++j) {
    const float x = exp2f((adj[j] - lm) * L2E);
    e[j] = msk[j] ? 0.f : x;
  }

  float ls = (e[0] + e[1]) + (e[2] + e[3]);
#pragma unroll
  for (int off = 32; off > 0; off >>= 1) ls += __shfl_xor(ls, off);

  const int p = q & 1;
  if (lane == 0) red[p][wid] = make_float2(lm, ls);
  asm volatile("s_waitcnt lgkmcnt(0)\n\ts_barrier" ::: "memory");

  const float2 v0 = red[p][0], v1 = red[p][1], v2 = red[p][2], v3 = red[p][3];
  const float2 v4 = red[p][4], v5 = red[p][5], v6 = red[p][6], v7 = red[p][7];
  const float M = fmaxf(fmaxf(fmaxf(v0.x, v1.x), fmaxf(v2.x, v3.x)),
                        fmaxf(fmaxf(v4.x, v5.x), fmaxf(v6.x, v7.x)));
  const float tot = v0.y * exp2f((v0.x - M) * L2E) + v1.y * exp2f((v1.x - M) * L2E) +
                    v2.y * exp2f((v2.x - M) * L2E) + v3.y * exp2f((v3.x - M) * L2E) +
                    v4.y * exp2f((v4.x - M) * L2E) + v5.y * exp2f((v5.x - M) * L2E) +
                    v6.y * exp2f((v6.x - M) * L2E) + v7.y * exp2f((v7.x - M) * L2E);
  const float scale = exp2f((lm - M) * L2E) / tot;

  f32x4 av;
#pragma unroll
  for (int j = 0; j < 4; ++j) {
    av[j] = e[j] * scale;
    acc[j] += av[j];
  }
  *(f32x4*)(attn + ((long)(q * B_ + b)) * S_ + s0) = av;
  uint2 pk;
  pk.x = (unsigned int)f2bf(av[0]) | ((unsigned int)f2bf(av[1]) << 16);
  pk.y = (unsigned int)f2bf(av[2]) | ((unsigned int)f2bf(av[3]) << 16);
  *(uint2*)(attnb + ((long)b * Q_ + q) * S_ + s0) = pk;
}

__global__ __launch_bounds__(512)
void scan_kernel(const int* __restrict__ mask, float* __restrict__ attn,
                 float* __restrict__ accum_out, unsigned short* __restrict__ attnb) {
  const int b = blockIdx.x;
  const int tid = threadIdx.x;
  const int lane = tid & 63;
  const int wid = tid >> 6;
  const int s0 = tid * 4;

  __shared__ float2 red[2][8];

  const int4 mk = *(const int4*)(mask + (long)b * S_ + s0);
  const bool msk[4] = {mk.x != 0, mk.y != 0, mk.z != 0, mk.w != 0};
  asm volatile("" :: "v"(mk.x), "v"(mk.y), "v"(mk.z), "v"(mk.w));

  float acc[4] = {0.f, 0.f, 0.f, 0.f};

  f32x4 bufE, bufO;
  const float* p0 = attn + (long)b * S_ + s0;
  asm volatile("global_load_dwordx4 %0, %1, off" : "=&v"(bufE) : "v"(p0) : "memory");
  const float* p1 = attn + ((long)(B_ + b)) * S_ + s0;
  asm volatile("global_load_dwordx4 %0, %1, off" : "=&v"(bufO) : "v"(p1) : "memory");

  scan_row<1>(attn, attnb, b, 0, lane, wid, s0, msk, acc, bufE, red);
  scan_row<3>(attn, attnb, b, 1, lane, wid, s0, msk, acc, bufO, red);
  for (int q = 2; q < Q_; q += 2) {
    scan_row<5>(attn, attnb, b, q,     lane, wid, s0, msk, acc, bufE, red);
    scan_row<5>(attn, attnb, b, q + 1, lane, wid, s0, msk, acc, bufO, red);
  }

  f32x4 a4;
#pragma unroll
  for (int j = 0; j < 4; ++j) a4[j] = acc[j];
  *(f32x4*)(accum_out + (long)b * S_ + s0) = a4;
}

extern "C" void kernel_launch(void* const* d_in, const int* in_sizes, int n_in,
                              void* d_out, int out_size, void* d_ws, size_t ws_size,
                              hipStream_t stream) {
  const float* ctx   = (const float*)d_in[0];  // [B,S,C] f32
  const float* query = (const float*)d_in[1];  // [Q,B,D] f32
  const int*   mask  = (const int*)d_in[2];    // [B,S] int32 (bool)
  const float* W     = (const float*)d_in[3];  // [C,D] f32

  float* out = (float*)d_out;
  float* attn = out;                                      // [Q,B,S]
  float* accum_out = out + (size_t)Q_ * B_ * S_;          // [B,1,S]
  float* comp = accum_out + (size_t)B_ * S_;              // [Q,B,C]

  char* ws = (char*)d_ws;
  float* qw = (float*)ws;                                                   // [B,Q,C] f32, 16 MiB
  unsigned short* ctxT  = (unsigned short*)(ws + (size_t)16 * 1024 * 1024); // [B,C,S] bf16, 128 MiB
  unsigned short* attnb = (unsigned short*)(ws + (size_t)16 * 1024 * 1024 +
                                            (size_t)B_ * C_ * S_ * 2);      // [B,Q,S] bf16, 16 MiB

  // 1) QW[b,q,c] = sum_d query[q,b,d] * W[c,d]  (3-pass split, DMA staging)
  gemm_f32<false><<<dim3(C_ / 128, (Q_ * B_) / 128, 1), 256, 65536, stream>>>(
      query, W, qw, D_, 0L, 0L, 0L, (long)D_, (long)D_, (long)C_, 1, nullptr, 0L);

  // 2) scores[q,b,s] = sum_c QW[b,q,c] * ctx[b,s,c]  + fused ctxT write-out
  gemm_f32<true><<<dim3(S_ / 128, 1, B_), 256, 65536, stream>>>(
      qw, ctx, attn, C_, (long)Q_ * C_, (long)S_ * C_, (long)S_,
      (long)C_, (long)C_, (long)B_ * S_, 0, ctxT, (long)S_);

  // 3) sequential coverage-softmax scan (in-place attention + accum + bf16 copy)
  scan_kernel<<<B_, 512, 0, stream>>>(mask, attn, accum_out, attnb);

  // 4) composition[q,b,c] = sum_s attnb[b,q,s] * ctxT[b,c,s]
  gemm_bf16<<<dim3(C_ / 128, 1, B_), 256, 32768, stream>>>(
      attnb, ctxT, comp, S_, (long)Q_ * S_, (long)C_ * S_, (long)C_,
      (long)S_, (long)S_, (long)B_ * C_);
}